// Round 1
// baseline (688.210 us; speedup 1.0000x reference)
//
#include <hip/hip_runtime.h>
#include <hip/hip_bf16.h>
#include <stdint.h>

#define B_   2
#define S_   2048
#define H_   2048
#define NH_  16
#define HD_  128
#define MTOT (B_*S_)   // 4096

typedef __attribute__((ext_vector_type(8))) short bf16x8;   // 8 bf16 = 4 VGPRs
typedef __attribute__((ext_vector_type(4))) float f32x4;    // MFMA C/D

// ---------------------------------------------------------------- cast fp32 -> bf16
__global__ void castk(const float* __restrict__ in, __hip_bfloat16* __restrict__ out, int n4) {
    int i = blockIdx.x * 256 + threadIdx.x;
    if (i < n4) {
        float4 v = *(const float4*)(in + (size_t)i * 4);
        out[(size_t)i*4 + 0] = __float2bfloat16(v.x);
        out[(size_t)i*4 + 1] = __float2bfloat16(v.y);
        out[(size_t)i*4 + 2] = __float2bfloat16(v.z);
        out[(size_t)i*4 + 3] = __float2bfloat16(v.w);
    }
}

// ---------------------------------------------------------------- NT GEMM: C[M,N] = A[M,K] * W[N,K]^T + bias
// 128x128 tile, BK=32, 4 waves, each wave 64x64 (4x4 MFMA tiles of 16x16x32)
#define APAD 40   // LDS row stride (32+8): 2-way bank aliasing (free), 16B-mult (80B)

template<int OUT_BF16>
__global__ __launch_bounds__(256)
void gemm_nt(const __hip_bfloat16* __restrict__ A,
             const __hip_bfloat16* __restrict__ W,
             const float* __restrict__ bias,
             void* __restrict__ Cout,
             int M, int N, int K)
{
    __shared__ __align__(16) __hip_bfloat16 As[128 * APAD];
    __shared__ __align__(16) __hip_bfloat16 Bs[128 * APAD];

    const int tid  = threadIdx.x;
    const int wave = tid >> 6, lane = tid & 63;
    const int quad = lane >> 4, l16 = lane & 15;
    const int wr = wave >> 1, wc = wave & 1;
    const int br = blockIdx.y, bc = blockIdx.x;

    f32x4 acc[4][4] = {};

    const __hip_bfloat16* Ablk = A + (size_t)(br * 128) * K;
    const __hip_bfloat16* Wblk = W + (size_t)(bc * 128) * K;

    for (int k0 = 0; k0 < K; k0 += 32) {
        // stage 128x32 bf16 tiles: 512 chunks of 16B, 2 per thread per matrix
#pragma unroll
        for (int t = 0; t < 2; ++t) {
            int chunk = t * 256 + tid;          // 0..511
            int row = chunk >> 2, cc = chunk & 3;
            *(float4*)(&As[row * APAD + cc * 8]) =
                *(const float4*)(Ablk + (size_t)row * K + k0 + cc * 8);
            *(float4*)(&Bs[row * APAD + cc * 8]) =
                *(const float4*)(Wblk + (size_t)row * K + k0 + cc * 8);
        }
        __syncthreads();

        bf16x8 af[4], bf[4];
#pragma unroll
        for (int i = 0; i < 4; ++i)
            af[i] = *(const bf16x8*)&As[(wr * 64 + i * 16 + l16) * APAD + quad * 8];
#pragma unroll
        for (int j = 0; j < 4; ++j)
            bf[j] = *(const bf16x8*)&Bs[(wc * 64 + j * 16 + l16) * APAD + quad * 8];

#pragma unroll
        for (int i = 0; i < 4; ++i)
#pragma unroll
            for (int j = 0; j < 4; ++j)
                acc[i][j] = __builtin_amdgcn_mfma_f32_16x16x32_bf16(af[i], bf[j], acc[i][j], 0, 0, 0);
        __syncthreads();
    }

    // epilogue: C[m = quad*4+reg (+16i+64wr), n = l16 (+16j+64wc)]
#pragma unroll
    for (int i = 0; i < 4; ++i) {
        int row = br * 128 + wr * 64 + i * 16 + quad * 4;
#pragma unroll
        for (int j = 0; j < 4; ++j) {
            int col = bc * 128 + wc * 64 + j * 16 + l16;
            float bv = bias[col];
#pragma unroll
            for (int r = 0; r < 4; ++r) {
                float v = acc[i][j][r] + bv;
                if (OUT_BF16)
                    ((__hip_bfloat16*)Cout)[(size_t)(row + r) * N + col] = __float2bfloat16(v);
                else
                    ((float*)Cout)[(size_t)(row + r) * N + col] = v;
            }
        }
    }
}

// ---------------------------------------------------------------- flash attention (causal)
// grid: (S/64, B*NH); block: 256 (4 waves); wave w handles 16 q-rows
#define KSTR 136   // Ks row stride (128+8)
#define VSTR 72    // VsT row stride (64+8)
#define PSTR 72    // Ps row stride (64+8)

__global__ __launch_bounds__(256)
void attn_kernel(const __hip_bfloat16* __restrict__ Q,
                 const __hip_bfloat16* __restrict__ K,
                 const __hip_bfloat16* __restrict__ V,
                 __hip_bfloat16* __restrict__ O)
{
    __shared__ __align__(16) __hip_bfloat16 Ks[64 * KSTR];     // K-tile row-major [n][d]
    __shared__ __align__(16) __hip_bfloat16 VsT[128 * VSTR];   // V-tile transposed [d][n]
    __shared__ __align__(16) __hip_bfloat16 Ps[4][16 * PSTR];  // per-wave P 16x64

    const int tid  = threadIdx.x;
    const int wave = tid >> 6, lane = tid & 63;
    const int quad = lane >> 4, l16 = lane & 15;
    const int qb = blockIdx.x;           // 0..31
    const int bh = blockIdx.y;           // 0..31
    const int b  = bh >> 4, h = bh & 15;

    const size_t headoff = (size_t)b * S_ * H_ + (size_t)h * HD_;
    const __hip_bfloat16* Qp = Q + headoff;
    const __hip_bfloat16* Kp = K + headoff;
    const __hip_bfloat16* Vp = V + headoff;

    const int qrow_local = wave * 16;              // within 64-row q-tile
    const int qrow = qb * 64 + qrow_local;

    // Q fragments: A-layout, rows qrow+l16, k-chunks of 32 over HD=128
    bf16x8 qf[4];
#pragma unroll
    for (int kd = 0; kd < 4; ++kd)
        qf[kd] = *(const bf16x8*)(Qp + (size_t)(qrow + l16) * H_ + kd * 32 + quad * 8);

    f32x4 oacc[8] = {};
    float mi[4], li[4];
#pragma unroll
    for (int r = 0; r < 4; ++r) { mi[r] = -1e30f; li[r] = 0.0f; }

    const float scale = 0.08838834764831843f;   // 1/sqrt(128)

    for (int kb = 0; kb <= qb; ++kb) {
        __syncthreads();
        // stage K-tile (64x128) row-major
#pragma unroll
        for (int t = 0; t < 4; ++t) {
            int chunk = t * 256 + tid;       // 0..1023
            int row = chunk >> 4, cc = chunk & 15;
            *(float4*)&Ks[row * KSTR + cc * 8] =
                *(const float4*)(Kp + (size_t)(kb * 64 + row) * H_ + cc * 8);
        }
        // stage V-tile transposed: VsT[d][n] = V[kb*64+n][d]
#pragma unroll
        for (int t = 0; t < 4; ++t) {
            int c = t * 256 + tid;           // 0..1023
            int n = c & 63, cc = c >> 6;     // cc wave-uniform
            float4 v4 = *(const float4*)(Vp + (size_t)(kb * 64 + n) * H_ + cc * 8);
            const __hip_bfloat16* vv = (const __hip_bfloat16*)&v4;
#pragma unroll
            for (int i = 0; i < 8; ++i)
                VsT[(cc * 8 + i) * VSTR + n] = vv[i];
        }
        __syncthreads();

        // S-tile: wave's 16 rows x 64 cols; C-layout col=l16(+16cb), row=quad*4+r
        f32x4 sacc[4] = {};
#pragma unroll
        for (int cb = 0; cb < 4; ++cb) {
#pragma unroll
            for (int kd = 0; kd < 4; ++kd) {
                bf16x8 kf = *(const bf16x8*)&Ks[(cb * 16 + l16) * KSTR + kd * 32 + quad * 8];
                sacc[cb] = __builtin_amdgcn_mfma_f32_16x16x32_bf16(qf[kd], kf, sacc[cb], 0, 0, 0);
            }
        }

        float p[4][4];   // [cb][r]
        const bool diag = (kb == qb);
#pragma unroll
        for (int cb = 0; cb < 4; ++cb) {
#pragma unroll
            for (int r = 0; r < 4; ++r) {
                float s = sacc[cb][r] * scale;
                if (diag) {
                    int col  = cb * 16 + l16;
                    int rowl = qrow_local + quad * 4 + r;
                    if (col > rowl) s = -1e30f;
                }
                p[cb][r] = s;
            }
        }

        // online softmax: row stats via 16-lane xor-shuffle reductions
        float alpha[4];
#pragma unroll
        for (int r = 0; r < 4; ++r) {
            float tm = fmaxf(fmaxf(p[0][r], p[1][r]), fmaxf(p[2][r], p[3][r]));
#pragma unroll
            for (int off = 1; off < 16; off <<= 1)
                tm = fmaxf(tm, __shfl_xor(tm, off));
            float mnew = fmaxf(mi[r], tm);
            float sum = 0.0f;
#pragma unroll
            for (int cb = 0; cb < 4; ++cb) {
                float e = __expf(p[cb][r] - mnew);
                p[cb][r] = e;
                sum += e;
            }
#pragma unroll
            for (int off = 1; off < 16; off <<= 1)
                sum += __shfl_xor(sum, off);
            alpha[r] = __expf(mi[r] - mnew);
            li[r] = li[r] * alpha[r] + sum;
            mi[r] = mnew;
        }
#pragma unroll
        for (int db = 0; db < 8; ++db)
#pragma unroll
            for (int r = 0; r < 4; ++r)
                oacc[db][r] *= alpha[r];

        // P (C-layout) -> LDS -> A-layout (verified m120 transform)
#pragma unroll
        for (int cb = 0; cb < 4; ++cb)
#pragma unroll
            for (int r = 0; r < 4; ++r)
                Ps[wave][(quad * 4 + r) * PSTR + cb * 16 + l16] = __float2bfloat16(p[cb][r]);
        __syncthreads();

        // O += P @ V : A=P (m=l16, k=quad*8+j), B=V^T-staged (n-col=l16 -> V[n][d])
#pragma unroll
        for (int ks = 0; ks < 2; ++ks) {
            bf16x8 pf = *(const bf16x8*)&Ps[wave][l16 * PSTR + ks * 32 + quad * 8];
#pragma unroll
            for (int db = 0; db < 8; ++db) {
                bf16x8 vf = *(const bf16x8*)&VsT[(db * 16 + l16) * VSTR + ks * 32 + quad * 8];
                oacc[db] = __builtin_amdgcn_mfma_f32_16x16x32_bf16(pf, vf, oacc[db], 0, 0, 0);
            }
        }
    }

    // epilogue: normalize and store bf16
#pragma unroll
    for (int db = 0; db < 8; ++db) {
#pragma unroll
        for (int r = 0; r < 4; ++r) {
            float v = oacc[db][r] / li[r];
            size_t row = (size_t)b * S_ + qb * 64 + qrow_local + quad * 4 + r;
            O[row * H_ + h * HD_ + db * 16 + l16] = __float2bfloat16(v);
        }
    }
}

// ---------------------------------------------------------------- launcher
extern "C" void kernel_launch(void* const* d_in, const int* in_sizes, int n_in,
                              void* d_out, int out_size, void* d_ws, size_t ws_size,
                              hipStream_t stream)
{
    const float* hs = (const float*)d_in[0];
    // d_in[1] = causal_mask (semantics baked in: strict upper triangle masked)
    const float* Wq = (const float*)d_in[2];
    const float* bq = (const float*)d_in[3];
    const float* Wk = (const float*)d_in[4];
    const float* bk = (const float*)d_in[5];
    const float* Wv = (const float*)d_in[6];
    const float* bv = (const float*)d_in[7];
    const float* Wo = (const float*)d_in[8];
    const float* bo = (const float*)d_in[9];

    const size_t szX = (size_t)MTOT * H_;   // 8.4M elems
    const size_t szW = (size_t)H_ * H_;     // 4.2M elems

    __hip_bfloat16* Xbf = (__hip_bfloat16*)d_ws;   // reused as attention output
    __hip_bfloat16* Wqb = Xbf + szX;
    __hip_bfloat16* Wkb = Wqb + szW;
    __hip_bfloat16* Wvb = Wkb + szW;
    __hip_bfloat16* Wob = Wvb + szW;
    __hip_bfloat16* Qb  = Wob + szW;
    __hip_bfloat16* Kb  = Qb + szX;
    __hip_bfloat16* Vb  = Kb + szX;

    // casts
    castk<<<(int)((szX/4 + 255)/256), 256, 0, stream>>>(hs, Xbf, (int)(szX/4));
    castk<<<(int)((szW/4 + 255)/256), 256, 0, stream>>>(Wq, Wqb, (int)(szW/4));
    castk<<<(int)((szW/4 + 255)/256), 256, 0, stream>>>(Wk, Wkb, (int)(szW/4));
    castk<<<(int)((szW/4 + 255)/256), 256, 0, stream>>>(Wv, Wvb, (int)(szW/4));
    castk<<<(int)((szW/4 + 255)/256), 256, 0, stream>>>(Wo, Wob, (int)(szW/4));

    dim3 ggrid(H_ / 128, MTOT / 128);   // (16, 32)
    gemm_nt<1><<<ggrid, 256, 0, stream>>>(Xbf, Wqb, bq, Qb, MTOT, H_, H_);
    gemm_nt<1><<<ggrid, 256, 0, stream>>>(Xbf, Wkb, bk, Kb, MTOT, H_, H_);
    gemm_nt<1><<<ggrid, 256, 0, stream>>>(Xbf, Wvb, bv, Vb, MTOT, H_, H_);

    dim3 agrid(S_ / 64, B_ * NH_);      // (32, 32)
    attn_kernel<<<agrid, 256, 0, stream>>>(Qb, Kb, Vb, Xbf);   // attn out overwrites Xbf

    gemm_nt<0><<<ggrid, 256, 0, stream>>>(Xbf, Wob, bo, d_out, MTOT, H_, H_);
}

// Round 2
// 603.708 us; speedup vs baseline: 1.1400x; 1.1400x over previous
//
#include <hip/hip_runtime.h>
#include <hip/hip_bf16.h>
#include <stdint.h>

#define B_   2
#define S_   2048
#define H_   2048
#define NH_  16
#define HD_  128
#define MTOT (B_*S_)   // 4096

typedef __attribute__((ext_vector_type(8))) short bf16x8;   // 8 bf16 = 4 VGPRs
typedef __attribute__((ext_vector_type(4))) float f32x4;    // MFMA C/D

// async global->LDS, 16B per lane; LDS dest = wave-uniform base + lane*16
__device__ __forceinline__ void gload_lds16(const void* g, void* l) {
    __builtin_amdgcn_global_load_lds(
        (const __attribute__((address_space(1))) void*)g,
        (__attribute__((address_space(3))) void*)l, 16, 0, 0);
}

// ---------------------------------------------------------------- cast fp32 -> bf16
__global__ void castk(const float* __restrict__ in, __hip_bfloat16* __restrict__ out, int n4) {
    int i = blockIdx.x * 256 + threadIdx.x;
    if (i < n4) {
        float4 v = *(const float4*)(in + (size_t)i * 4);
        out[(size_t)i*4 + 0] = __float2bfloat16(v.x);
        out[(size_t)i*4 + 1] = __float2bfloat16(v.y);
        out[(size_t)i*4 + 2] = __float2bfloat16(v.z);
        out[(size_t)i*4 + 3] = __float2bfloat16(v.w);
    }
}

// ---------------------------------------------------------------- NT GEMM: C[M,N] = A[M,K] * W[N,K]^T + bias
// m97 structure: 128x128 tile, BK=32, global_load_lds width-16 staging, unpadded LDS
template<int OUT_BF16>
__global__ __launch_bounds__(256)
void gemm_nt(const __hip_bfloat16* __restrict__ A,
             const __hip_bfloat16* __restrict__ W,
             const float* __restrict__ bias,
             void* __restrict__ Cout,
             int M, int N, int K)
{
    __shared__ __align__(16) __hip_bfloat16 As[128 * 32];   // row-major, K-contig, unpadded
    __shared__ __align__(16) __hip_bfloat16 Bs[128 * 32];

    const int tid  = threadIdx.x;
    const int wave = tid >> 6, lane = tid & 63;
    const int quad = lane >> 4, l16 = lane & 15;
    const int wr = wave >> 1, wc = wave & 1;
    const int br = blockIdx.y, bc = blockIdx.x;

    f32x4 acc[4][4] = {};

    const __hip_bfloat16* Ablk = A + (size_t)(br * 128) * K;
    const __hip_bfloat16* Wblk = W + (size_t)(bc * 128) * K;

    for (int k0 = 0; k0 < K; k0 += 32) {
        // 512 x 16B chunks per matrix; chunk c -> row=c>>2, col-chunk=c&3, LDS byte off = c*16
#pragma unroll
        for (int t = 0; t < 2; ++t) {
            int c = t * 256 + wave * 64 + lane;
            int row = c >> 2, cc = c & 3;
            int base = (t * 256 + wave * 64) * 16;       // wave-uniform
            gload_lds16(Ablk + (size_t)row * K + k0 + cc * 8, (char*)As + base);
            gload_lds16(Wblk + (size_t)row * K + k0 + cc * 8, (char*)Bs + base);
        }
        __syncthreads();

        bf16x8 af[4], bf[4];
#pragma unroll
        for (int i = 0; i < 4; ++i)
            af[i] = *(const bf16x8*)&As[(wr * 64 + i * 16 + l16) * 32 + quad * 8];
#pragma unroll
        for (int j = 0; j < 4; ++j)
            bf[j] = *(const bf16x8*)&Bs[(wc * 64 + j * 16 + l16) * 32 + quad * 8];

#pragma unroll
        for (int i = 0; i < 4; ++i)
#pragma unroll
            for (int j = 0; j < 4; ++j)
                acc[i][j] = __builtin_amdgcn_mfma_f32_16x16x32_bf16(af[i], bf[j], acc[i][j], 0, 0, 0);
        __syncthreads();
    }

    // epilogue: C[m = quad*4+reg (+16i+64wr), n = l16 (+16j+64wc)]
#pragma unroll
    for (int i = 0; i < 4; ++i) {
        int row = br * 128 + wr * 64 + i * 16 + quad * 4;
#pragma unroll
        for (int j = 0; j < 4; ++j) {
            int col = bc * 128 + wc * 64 + j * 16 + l16;
            float bv = bias[col];
#pragma unroll
            for (int r = 0; r < 4; ++r) {
                float v = acc[i][j][r] + bv;
                if (OUT_BF16)
                    ((__hip_bfloat16*)Cout)[(size_t)(row + r) * N + col] = __float2bfloat16(v);
                else
                    ((float*)Cout)[(size_t)(row + r) * N + col] = v;
            }
        }
    }
}

// ---------------------------------------------------------------- flash attention (causal, pair-balanced)
// grid: (16, B*NH); block p handles q-tiles (31-p) then (p) => exactly 33 K-iters per block
#define KSTR 136   // Ks row stride (128+8)
#define VSTR 72    // VsT row stride (64+8)
#define PSTR 72    // Ps row stride (64+8)

__global__ __launch_bounds__(256)
void attn_kernel(const __hip_bfloat16* __restrict__ Q,
                 const __hip_bfloat16* __restrict__ K,
                 const __hip_bfloat16* __restrict__ V,
                 __hip_bfloat16* __restrict__ O)
{
    __shared__ __align__(16) __hip_bfloat16 Ks[64 * KSTR];     // K-tile row-major [n][d]
    __shared__ __align__(16) __hip_bfloat16 VsT[128 * VSTR];   // V-tile transposed [d][n]
    __shared__ __align__(16) __hip_bfloat16 Ps[4][16 * PSTR];  // per-wave P 16x64 (wave-private)

    const int tid  = threadIdx.x;
    const int wave = tid >> 6, lane = tid & 63;
    const int quad = lane >> 4, l16 = lane & 15;
    const int pr = blockIdx.x;           // pair index 0..15
    const int bh = blockIdx.y;           // 0..31
    const int b  = bh >> 4, h = bh & 15;

    const size_t headoff = (size_t)b * S_ * H_ + (size_t)h * HD_;
    const __hip_bfloat16* Qp = Q + headoff;
    const __hip_bfloat16* Kp = K + headoff;
    const __hip_bfloat16* Vp = V + headoff;

    const float scale = 0.08838834764831843f;   // 1/sqrt(128)

    for (int which = 0; which < 2; ++which) {
        const int qb = which ? pr : 31 - pr;
        const int qrow_local = wave * 16;
        const int qrow = qb * 64 + qrow_local;

        // Q fragments: A-layout, rows qrow+l16, k-chunks of 32 over HD=128
        bf16x8 qf[4];
#pragma unroll
        for (int kd = 0; kd < 4; ++kd)
            qf[kd] = *(const bf16x8*)(Qp + (size_t)(qrow + l16) * H_ + kd * 32 + quad * 8);

        f32x4 oacc[8] = {};
        float mi[4], li[4];
#pragma unroll
        for (int r = 0; r < 4; ++r) { mi[r] = -1e30f; li[r] = 0.0f; }

        // ---- prologue: stage kb=0 tile (through regs so the barrier placement is uniform)
        float4 kr[4], vr[4];
#pragma unroll
        for (int t = 0; t < 4; ++t) {
            int c = t * 256 + tid;
            kr[t] = *(const float4*)(Kp + (size_t)(c >> 4) * H_ + (c & 15) * 8);
            vr[t] = *(const float4*)(Vp + (size_t)(c & 63) * H_ + (c >> 6) * 8);
        }
        __syncthreads();   // prior tile's readers done before overwriting LDS
#pragma unroll
        for (int t = 0; t < 4; ++t) {
            int c = t * 256 + tid;
            *(float4*)&Ks[(c >> 4) * KSTR + (c & 15) * 8] = kr[t];
            const __hip_bfloat16* vv = (const __hip_bfloat16*)&vr[t];
            int n = c & 63, cc = c >> 6;
#pragma unroll
            for (int i = 0; i < 8; ++i)
                VsT[(cc * 8 + i) * VSTR + n] = vv[i];
        }
        __syncthreads();

        for (int kb = 0; kb <= qb; ++kb) {
            const bool more = (kb < qb);
            // ---- prefetch next K/V tile into registers (issued before compute)
            float4 kr2[4], vr2[4];
            if (more) {
                const __hip_bfloat16* Kn = Kp + (size_t)(kb + 1) * 64 * H_;
                const __hip_bfloat16* Vn = Vp + (size_t)(kb + 1) * 64 * H_;
#pragma unroll
                for (int t = 0; t < 4; ++t) {
                    int c = t * 256 + tid;
                    kr2[t] = *(const float4*)(Kn + (size_t)(c >> 4) * H_ + (c & 15) * 8);
                    vr2[t] = *(const float4*)(Vn + (size_t)(c & 63) * H_ + (c >> 6) * 8);
                }
            }

            // ---- S-tile: wave's 16 rows x 64 cols
            f32x4 sacc[4] = {};
#pragma unroll
            for (int cb = 0; cb < 4; ++cb) {
#pragma unroll
                for (int kd = 0; kd < 4; ++kd) {
                    bf16x8 kf = *(const bf16x8*)&Ks[(cb * 16 + l16) * KSTR + kd * 32 + quad * 8];
                    sacc[cb] = __builtin_amdgcn_mfma_f32_16x16x32_bf16(qf[kd], kf, sacc[cb], 0, 0, 0);
                }
            }

            float p[4][4];   // [cb][r]
            const bool diag = (kb == qb);
#pragma unroll
            for (int cb = 0; cb < 4; ++cb) {
#pragma unroll
                for (int r = 0; r < 4; ++r) {
                    float s = sacc[cb][r] * scale;
                    if (diag) {
                        int col  = cb * 16 + l16;
                        int rowl = qrow_local + quad * 4 + r;
                        if (col > rowl) s = -1e30f;
                    }
                    p[cb][r] = s;
                }
            }

            // ---- online softmax (16-lane xor-shuffle row reductions)
            float alpha[4];
#pragma unroll
            for (int r = 0; r < 4; ++r) {
                float tm = fmaxf(fmaxf(p[0][r], p[1][r]), fmaxf(p[2][r], p[3][r]));
#pragma unroll
                for (int off = 1; off < 16; off <<= 1)
                    tm = fmaxf(tm, __shfl_xor(tm, off));
                float mnew = fmaxf(mi[r], tm);
                float sum = 0.0f;
#pragma unroll
                for (int cb = 0; cb < 4; ++cb) {
                    float e = __expf(p[cb][r] - mnew);
                    p[cb][r] = e;
                    sum += e;
                }
#pragma unroll
                for (int off = 1; off < 16; off <<= 1)
                    sum += __shfl_xor(sum, off);
                alpha[r] = __expf(mi[r] - mnew);
                li[r] = li[r] * alpha[r] + sum;
                mi[r] = mnew;
            }
#pragma unroll
            for (int db = 0; db < 8; ++db)
#pragma unroll
                for (int r = 0; r < 4; ++r)
                    oacc[db][r] *= alpha[r];

            // ---- P (C-layout) -> LDS -> A-layout; Ps is wave-private, no barrier needed
#pragma unroll
            for (int cb = 0; cb < 4; ++cb)
#pragma unroll
                for (int r = 0; r < 4; ++r)
                    Ps[wave][(quad * 4 + r) * PSTR + cb * 16 + l16] = __float2bfloat16(p[cb][r]);

            // ---- O += P @ V
#pragma unroll
            for (int ks = 0; ks < 2; ++ks) {
                bf16x8 pf = *(const bf16x8*)&Ps[wave][l16 * PSTR + ks * 32 + quad * 8];
#pragma unroll
                for (int db = 0; db < 8; ++db) {
                    bf16x8 vf = *(const bf16x8*)&VsT[(db * 16 + l16) * VSTR + ks * 32 + quad * 8];
                    oacc[db] = __builtin_amdgcn_mfma_f32_16x16x32_bf16(pf, vf, oacc[db], 0, 0, 0);
                }
            }

            // ---- stage prefetched tile
            if (more) {
                __syncthreads();   // all waves done reading current tile
#pragma unroll
                for (int t = 0; t < 4; ++t) {
                    int c = t * 256 + tid;
                    *(float4*)&Ks[(c >> 4) * KSTR + (c & 15) * 8] = kr2[t];
                    const __hip_bfloat16* vv = (const __hip_bfloat16*)&vr2[t];
                    int n = c & 63, cc = c >> 6;
#pragma unroll
                    for (int i = 0; i < 8; ++i)
                        VsT[(cc * 8 + i) * VSTR + n] = vv[i];
                }
                __syncthreads();
            }
        }

        // ---- epilogue: normalize and store bf16
#pragma unroll
        for (int db = 0; db < 8; ++db) {
#pragma unroll
            for (int r = 0; r < 4; ++r) {
                float v = oacc[db][r] / li[r];
                size_t row = (size_t)b * S_ + qb * 64 + qrow_local + quad * 4 + r;
                O[row * H_ + h * HD_ + db * 16 + l16] = __float2bfloat16(v);
            }
        }
    }
}

// ---------------------------------------------------------------- launcher
extern "C" void kernel_launch(void* const* d_in, const int* in_sizes, int n_in,
                              void* d_out, int out_size, void* d_ws, size_t ws_size,
                              hipStream_t stream)
{
    const float* hs = (const float*)d_in[0];
    // d_in[1] = causal_mask (semantics baked in: strict upper triangle masked)
    const float* Wq = (const float*)d_in[2];
    const float* bq = (const float*)d_in[3];
    const float* Wk = (const float*)d_in[4];
    const float* bk = (const float*)d_in[5];
    const float* Wv = (const float*)d_in[6];
    const float* bv = (const float*)d_in[7];
    const float* Wo = (const float*)d_in[8];
    const float* bo = (const float*)d_in[9];

    const size_t szX = (size_t)MTOT * H_;   // 8.4M elems
    const size_t szW = (size_t)H_ * H_;     // 4.2M elems

    __hip_bfloat16* Xbf = (__hip_bfloat16*)d_ws;   // reused as attention output
    __hip_bfloat16* Wqb = Xbf + szX;
    __hip_bfloat16* Wkb = Wqb + szW;
    __hip_bfloat16* Wvb = Wkb + szW;
    __hip_bfloat16* Wob = Wvb + szW;
    __hip_bfloat16* Qb  = Wob + szW;
    __hip_bfloat16* Kb  = Qb + szX;
    __hip_bfloat16* Vb  = Kb + szX;

    castk<<<(int)((szX/4 + 255)/256), 256, 0, stream>>>(hs, Xbf, (int)(szX/4));
    castk<<<(int)((szW/4 + 255)/256), 256, 0, stream>>>(Wq, Wqb, (int)(szW/4));
    castk<<<(int)((szW/4 + 255)/256), 256, 0, stream>>>(Wk, Wkb, (int)(szW/4));
    castk<<<(int)((szW/4 + 255)/256), 256, 0, stream>>>(Wv, Wvb, (int)(szW/4));
    castk<<<(int)((szW/4 + 255)/256), 256, 0, stream>>>(Wo, Wob, (int)(szW/4));

    dim3 ggrid(H_ / 128, MTOT / 128);   // (16, 32)
    gemm_nt<1><<<ggrid, 256, 0, stream>>>(Xbf, Wqb, bq, Qb, MTOT, H_, H_);
    gemm_nt<1><<<ggrid, 256, 0, stream>>>(Xbf, Wkb, bk, Kb, MTOT, H_, H_);
    gemm_nt<1><<<ggrid, 256, 0, stream>>>(Xbf, Wvb, bv, Vb, MTOT, H_, H_);

    dim3 agrid(16, B_ * NH_);           // pair-balanced: 512 blocks, 33 iters each
    attn_kernel<<<agrid, 256, 0, stream>>>(Qb, Kb, Vb, Xbf);   // attn out overwrites Xbf

    gemm_nt<0><<<ggrid, 256, 0, stream>>>(Xbf, Wob, bo, d_out, MTOT, H_, H_);
}

// Round 3
// 489.223 us; speedup vs baseline: 1.4067x; 1.2340x over previous
//
#include <hip/hip_runtime.h>
#include <hip/hip_bf16.h>
#include <stdint.h>

#define B_   2
#define S_   2048
#define H_   2048
#define NH_  16
#define HD_  128
#define MTOT (B_*S_)   // 4096

typedef __attribute__((ext_vector_type(8))) short bf16x8;   // 8 bf16 = 4 VGPRs
typedef __attribute__((ext_vector_type(4))) float f32x4;    // MFMA C/D

// async global->LDS, 16B per lane; LDS dest = wave-uniform base + lane*16
__device__ __forceinline__ void gload_lds16(const void* g, void* l) {
    __builtin_amdgcn_global_load_lds(
        (const __attribute__((address_space(1))) void*)g,
        (__attribute__((address_space(3))) void*)l, 16, 0, 0);
}

// ---------------------------------------------------------------- casts fp32 -> bf16
__global__ void castk(const float* __restrict__ in, __hip_bfloat16* __restrict__ out, int n4) {
    int i = blockIdx.x * 256 + threadIdx.x;
    if (i < n4) {
        float4 v = *(const float4*)(in + (size_t)i * 4);
        out[(size_t)i*4 + 0] = __float2bfloat16(v.x);
        out[(size_t)i*4 + 1] = __float2bfloat16(v.y);
        out[(size_t)i*4 + 2] = __float2bfloat16(v.z);
        out[(size_t)i*4 + 3] = __float2bfloat16(v.w);
    }
}

__global__ void castw4(const float* __restrict__ w0, const float* __restrict__ w1,
                       const float* __restrict__ w2, const float* __restrict__ w3,
                       __hip_bfloat16* o0, __hip_bfloat16* o1,
                       __hip_bfloat16* o2, __hip_bfloat16* o3, int n4) {
    const float* in; __hip_bfloat16* out;
    switch (blockIdx.y) {
        case 0:  in = w0; out = o0; break;
        case 1:  in = w1; out = o1; break;
        case 2:  in = w2; out = o2; break;
        default: in = w3; out = o3; break;
    }
    int i = blockIdx.x * 256 + threadIdx.x;
    if (i < n4) {
        float4 v = *(const float4*)(in + (size_t)i * 4);
        out[(size_t)i*4 + 0] = __float2bfloat16(v.x);
        out[(size_t)i*4 + 1] = __float2bfloat16(v.y);
        out[(size_t)i*4 + 2] = __float2bfloat16(v.z);
        out[(size_t)i*4 + 3] = __float2bfloat16(v.w);
    }
}

// ---------------------------------------------------------------- NT GEMM (m97 structure, unchanged)
template<int OUT_BF16>
__global__ __launch_bounds__(256)
void gemm_nt(const __hip_bfloat16* __restrict__ A,
             const __hip_bfloat16* __restrict__ W,
             const float* __restrict__ bias,
             void* __restrict__ Cout,
             int M, int N, int K)
{
    __shared__ __align__(16) __hip_bfloat16 As[128 * 32];
    __shared__ __align__(16) __hip_bfloat16 Bs[128 * 32];

    const int tid  = threadIdx.x;
    const int wave = tid >> 6, lane = tid & 63;
    const int quad = lane >> 4, l16 = lane & 15;
    const int wr = wave >> 1, wc = wave & 1;
    const int br = blockIdx.y, bc = blockIdx.x;

    f32x4 acc[4][4] = {};

    const __hip_bfloat16* Ablk = A + (size_t)(br * 128) * K;
    const __hip_bfloat16* Wblk = W + (size_t)(bc * 128) * K;

    for (int k0 = 0; k0 < K; k0 += 32) {
#pragma unroll
        for (int t = 0; t < 2; ++t) {
            int c = t * 256 + wave * 64 + lane;
            int row = c >> 2, cc = c & 3;
            int base = (t * 256 + wave * 64) * 16;       // wave-uniform
            gload_lds16(Ablk + (size_t)row * K + k0 + cc * 8, (char*)As + base);
            gload_lds16(Wblk + (size_t)row * K + k0 + cc * 8, (char*)Bs + base);
        }
        __syncthreads();

        bf16x8 af[4], bf[4];
#pragma unroll
        for (int i = 0; i < 4; ++i)
            af[i] = *(const bf16x8*)&As[(wr * 64 + i * 16 + l16) * 32 + quad * 8];
#pragma unroll
        for (int j = 0; j < 4; ++j)
            bf[j] = *(const bf16x8*)&Bs[(wc * 64 + j * 16 + l16) * 32 + quad * 8];

#pragma unroll
        for (int i = 0; i < 4; ++i)
#pragma unroll
            for (int j = 0; j < 4; ++j)
                acc[i][j] = __builtin_amdgcn_mfma_f32_16x16x32_bf16(af[i], bf[j], acc[i][j], 0, 0, 0);
        __syncthreads();
    }

#pragma unroll
    for (int i = 0; i < 4; ++i) {
        int row = br * 128 + wr * 64 + i * 16 + quad * 4;
#pragma unroll
        for (int j = 0; j < 4; ++j) {
            int col = bc * 128 + wc * 64 + j * 16 + l16;
            float bv = bias[col];
#pragma unroll
            for (int r = 0; r < 4; ++r) {
                float v = acc[i][j][r] + bv;
                if (OUT_BF16)
                    ((__hip_bfloat16*)Cout)[(size_t)(row + r) * N + col] = __float2bfloat16(v);
                else
                    ((float*)Cout)[(size_t)(row + r) * N + col] = v;
            }
        }
    }
}

// ---------------------------------------------------------------- flash attention v3
// XCD-pinned 1D grid; K double-buffered via global_load_lds + XOR swizzle; V register-prefetch.
#define VSTR 72    // VsT row stride (64+8)
#define PSTR 72    // Ps row stride (64+8)

__global__ __launch_bounds__(256)
void attn_kernel(const __hip_bfloat16* __restrict__ Q,
                 const __hip_bfloat16* __restrict__ K,
                 const __hip_bfloat16* __restrict__ V,
                 __hip_bfloat16* __restrict__ O)
{
    // Ks: [buf][row 0..63][chunk 0..15] of 16B; element (row, col) stored at
    // chunk (col/8) ^ (row&7)  -> global_load_lds-compatible (unpadded) + conflict-free b128 reads
    __shared__ __align__(16) char KsB[2][64 * 256];            // 32 KB
    __shared__ __align__(16) __hip_bfloat16 VsT[128 * VSTR];   // 18 KB, [d][n] transposed
    __shared__ __align__(16) __hip_bfloat16 Ps[4][16 * PSTR];  // 9 KB, per-wave P 16x64

    const int tid  = threadIdx.x;
    const int wave = tid >> 6, lane = tid & 63;
    const int quad = lane >> 4, l16 = lane & 15;

    // XCD-pinning swizzle: all 16 blocks of one (b,h) on one XCD (RR heuristic)
    const int lid  = blockIdx.x;            // 0..511
    const int xcd  = lid & 7;
    const int slot = lid >> 3;              // 0..63
    const int bh   = ((slot >> 4) << 3) | xcd;   // 0..31
    const int pr   = slot & 15;             // pair index 0..15
    const int b    = bh >> 4, h = bh & 15;

    const size_t headoff = (size_t)b * S_ * H_ + (size_t)h * HD_;
    const __hip_bfloat16* Qp = Q + headoff;
    const __hip_bfloat16* Kp = K + headoff;
    const __hip_bfloat16* Vp = V + headoff;

    const float scale = 0.08838834764831843f;   // 1/sqrt(128)

    for (int which = 0; which < 2; ++which) {
        const int qb = which ? pr : 31 - pr;
        const int qrow_local = wave * 16;
        const int qrow = qb * 64 + qrow_local;

        bf16x8 qf[4];
#pragma unroll
        for (int kd = 0; kd < 4; ++kd)
            qf[kd] = *(const bf16x8*)(Qp + (size_t)(qrow + l16) * H_ + kd * 32 + quad * 8);

        f32x4 oacc[8] = {};
        float mi[4], li[4];
#pragma unroll
        for (int r = 0; r < 4; ++r) { mi[r] = -1e30f; li[r] = 0.0f; }

        int bb = 0;

        // ---- prologue: stage tile 0 (K async -> KsB[0]; V via regs -> VsT)
        {
#pragma unroll
            for (int t = 0; t < 4; ++t) {
                int c = wave * 256 + t * 64 + lane;
                int row = c >> 4, pos = c & 15;
                int g = pos ^ (row & 7);
                gload_lds16(Kp + (size_t)row * H_ + g * 8,
                            &KsB[0][wave * 4096 + t * 1024]);
            }
            float4 vr[4];
#pragma unroll
            for (int t = 0; t < 4; ++t) {
                int c = t * 256 + tid;
                vr[t] = *(const float4*)(Vp + (size_t)(c & 63) * H_ + (c >> 6) * 8);
            }
            __syncthreads();   // prev q-tile's readers done with VsT/Ks
#pragma unroll
            for (int t = 0; t < 4; ++t) {
                int c = t * 256 + tid;
                const __hip_bfloat16* vv = (const __hip_bfloat16*)&vr[t];
                int n = c & 63, cc = c >> 6;
#pragma unroll
                for (int i = 0; i < 8; ++i)
                    VsT[(cc * 8 + i) * VSTR + n] = vv[i];
            }
            __syncthreads();
        }

        for (int kb = 0; kb <= qb; ++kb) {
            const bool more = (kb < qb);
            const int nb = bb ^ 1;

            // ---- async K prefetch straight to LDS[nb]; V prefetch to regs
            float4 vr2[4];
            if (more) {
                const __hip_bfloat16* Kn = Kp + (size_t)(kb + 1) * 64 * H_;
                const __hip_bfloat16* Vn = Vp + (size_t)(kb + 1) * 64 * H_;
#pragma unroll
                for (int t = 0; t < 4; ++t) {
                    int c = wave * 256 + t * 64 + lane;
                    int row = c >> 4, pos = c & 15;
                    int g = pos ^ (row & 7);
                    gload_lds16(Kn + (size_t)row * H_ + g * 8,
                                &KsB[nb][wave * 4096 + t * 1024]);
                }
#pragma unroll
                for (int t = 0; t < 4; ++t) {
                    int c = t * 256 + tid;
                    vr2[t] = *(const float4*)(Vn + (size_t)(c & 63) * H_ + (c >> 6) * 8);
                }
            }

            // ---- S-tile: QK^T from swizzled KsB[bb]
            f32x4 sacc[4] = {};
#pragma unroll
            for (int cb = 0; cb < 4; ++cb) {
#pragma unroll
                for (int kd = 0; kd < 4; ++kd) {
                    int row = cb * 16 + l16;
                    int pos = (4 * kd + quad) ^ (l16 & 7);
                    bf16x8 kf = *(const bf16x8*)&KsB[bb][row * 256 + pos * 16];
                    sacc[cb] = __builtin_amdgcn_mfma_f32_16x16x32_bf16(qf[kd], kf, sacc[cb], 0, 0, 0);
                }
            }

            float p[4][4];
            const bool diag = (kb == qb);
#pragma unroll
            for (int cb = 0; cb < 4; ++cb) {
#pragma unroll
                for (int r = 0; r < 4; ++r) {
                    float s = sacc[cb][r] * scale;
                    if (diag) {
                        int col  = cb * 16 + l16;
                        int rowl = qrow_local + quad * 4 + r;
                        if (col > rowl) s = -1e30f;
                    }
                    p[cb][r] = s;
                }
            }

            // ---- online softmax
            float alpha[4];
#pragma unroll
            for (int r = 0; r < 4; ++r) {
                float tm = fmaxf(fmaxf(p[0][r], p[1][r]), fmaxf(p[2][r], p[3][r]));
#pragma unroll
                for (int off = 1; off < 16; off <<= 1)
                    tm = fmaxf(tm, __shfl_xor(tm, off));
                float mnew = fmaxf(mi[r], tm);
                float sum = 0.0f;
#pragma unroll
                for (int cb = 0; cb < 4; ++cb) {
                    float e = __expf(p[cb][r] - mnew);
                    p[cb][r] = e;
                    sum += e;
                }
#pragma unroll
                for (int off = 1; off < 16; off <<= 1)
                    sum += __shfl_xor(sum, off);
                alpha[r] = __expf(mi[r] - mnew);
                li[r] = li[r] * alpha[r] + sum;
                mi[r] = mnew;
            }
#pragma unroll
            for (int db = 0; db < 8; ++db)
#pragma unroll
                for (int r = 0; r < 4; ++r)
                    oacc[db][r] *= alpha[r];

            // ---- P (C-layout) -> LDS -> A-layout (wave-private, no barrier)
#pragma unroll
            for (int cb = 0; cb < 4; ++cb)
#pragma unroll
                for (int r = 0; r < 4; ++r)
                    Ps[wave][(quad * 4 + r) * PSTR + cb * 16 + l16] = __float2bfloat16(p[cb][r]);

            // ---- O += P @ V
#pragma unroll
            for (int ks = 0; ks < 2; ++ks) {
                bf16x8 pf = *(const bf16x8*)&Ps[wave][l16 * PSTR + ks * 32 + quad * 8];
#pragma unroll
                for (int db = 0; db < 8; ++db) {
                    bf16x8 vf = *(const bf16x8*)&VsT[(db * 16 + l16) * VSTR + ks * 32 + quad * 8];
                    oacc[db] = __builtin_amdgcn_mfma_f32_16x16x32_bf16(pf, vf, oacc[db], 0, 0, 0);
                }
            }

            // ---- stage prefetched V (single-buffered VsT needs the barrier pair)
            if (more) {
                __syncthreads();   // all waves done reading VsT
#pragma unroll
                for (int t = 0; t < 4; ++t) {
                    int c = t * 256 + tid;
                    const __hip_bfloat16* vv = (const __hip_bfloat16*)&vr2[t];
                    int n = c & 63, cc = c >> 6;
#pragma unroll
                    for (int i = 0; i < 8; ++i)
                        VsT[(cc * 8 + i) * VSTR + n] = vv[i];
                }
                __syncthreads();   // VsT + KsB[nb] (vmcnt-drained) visible to all
            }
            bb = nb;
        }

        // ---- epilogue
#pragma unroll
        for (int db = 0; db < 8; ++db) {
#pragma unroll
            for (int r = 0; r < 4; ++r) {
                float v = oacc[db][r] / li[r];
                size_t row = (size_t)b * S_ + qb * 64 + qrow_local + quad * 4 + r;
                O[row * H_ + h * HD_ + db * 16 + l16] = __float2bfloat16(v);
            }
        }
        __syncthreads();   // protect KsB/VsT before next which's prologue overwrites
    }
}

// ---------------------------------------------------------------- launcher
extern "C" void kernel_launch(void* const* d_in, const int* in_sizes, int n_in,
                              void* d_out, int out_size, void* d_ws, size_t ws_size,
                              hipStream_t stream)
{
    const float* hs = (const float*)d_in[0];
    const float* Wq = (const float*)d_in[2];
    const float* bq = (const float*)d_in[3];
    const float* Wk = (const float*)d_in[4];
    const float* bk = (const float*)d_in[5];
    const float* Wv = (const float*)d_in[6];
    const float* bv = (const float*)d_in[7];
    const float* Wo = (const float*)d_in[8];
    const float* bo = (const float*)d_in[9];

    const size_t szX = (size_t)MTOT * H_;
    const size_t szW = (size_t)H_ * H_;

    __hip_bfloat16* Xbf = (__hip_bfloat16*)d_ws;   // reused as attention output
    __hip_bfloat16* Wqb = Xbf + szX;
    __hip_bfloat16* Wkb = Wqb + szW;
    __hip_bfloat16* Wvb = Wkb + szW;
    __hip_bfloat16* Wob = Wvb + szW;
    __hip_bfloat16* Qb  = Wob + szW;
    __hip_bfloat16* Kb  = Qb + szX;
    __hip_bfloat16* Vb  = Kb + szX;

    castk<<<(int)((szX/4 + 255)/256), 256, 0, stream>>>(hs, Xbf, (int)(szX/4));
    dim3 wgrid((unsigned)((szW/4 + 255)/256), 4);
    castw4<<<wgrid, 256, 0, stream>>>(Wq, Wk, Wv, Wo, Wqb, Wkb, Wvb, Wob, (int)(szW/4));

    dim3 ggrid(H_ / 128, MTOT / 128);   // (16, 32)
    gemm_nt<1><<<ggrid, 256, 0, stream>>>(Xbf, Wqb, bq, Qb, MTOT, H_, H_);
    gemm_nt<1><<<ggrid, 256, 0, stream>>>(Xbf, Wkb, bk, Kb, MTOT, H_, H_);
    gemm_nt<1><<<ggrid, 256, 0, stream>>>(Xbf, Wvb, bv, Vb, MTOT, H_, H_);

    attn_kernel<<<dim3(512), 256, 0, stream>>>(Qb, Kb, Vb, Xbf);

    gemm_nt<0><<<ggrid, 256, 0, stream>>>(Xbf, Wob, bo, d_out, MTOT, H_, H_);
}